// Round 1
// baseline (154.311 us; speedup 1.0000x reference)
//
#include <hip/hip_runtime.h>
#include <hip/hip_bf16.h>
#include <stdint.h>

#define B_N 4096
#define V_N 2
#define D_N 1024
#define EPS 1e-8f

typedef __attribute__((ext_vector_type(8))) short short8;
typedef __attribute__((ext_vector_type(4))) float f32x4;

__device__ __forceinline__ unsigned int f2mono(float f) {
    unsigned int u = __float_as_uint(f);
    return (u & 0x80000000u) ? ~u : (u | 0x80000000u);
}

__device__ __forceinline__ unsigned short f2bf(float f) {
    __hip_bfloat16 h = __float2bfloat16(f);
    return __builtin_bit_cast(unsigned short, h);
}

__device__ __forceinline__ unsigned long long shfl_xor_u64(unsigned long long v, int m) {
    unsigned int lo = (unsigned int)v, hi = (unsigned int)(v >> 32);
    lo = __shfl_xor(lo, m, 64);
    hi = __shfl_xor(hi, m, 64);
    return ((unsigned long long)hi << 32) | lo;
}

// ---------------- Kernel 1: L2-normalize, emit bf16 (V,B,D) ----------------
__global__ __launch_bounds__(256) void knorm(const float* __restrict__ x,
                                             unsigned short* __restrict__ xbf) {
    int r = blockIdx.x;            // r = b*V + v  (input rows are contiguous)
    int b = r >> 1, v = r & 1;
    const float* row = x + (size_t)r * D_N;
    int t = threadIdx.x;
    float4 val = reinterpret_cast<const float4*>(row)[t];
    float ss = val.x * val.x + val.y * val.y + val.z * val.z + val.w * val.w;
    #pragma unroll
    for (int s = 32; s > 0; s >>= 1) ss += __shfl_xor(ss, s, 64);
    __shared__ float wsum[4];
    if ((t & 63) == 0) wsum[t >> 6] = ss;
    __syncthreads();
    float tot = wsum[0] + wsum[1] + wsum[2] + wsum[3];
    float rn = 1.0f / sqrtf(tot + EPS);
    ushort4 o;
    o.x = f2bf(val.x * rn);
    o.y = f2bf(val.y * rn);
    o.z = f2bf(val.z * rn);
    o.w = f2bf(val.w * rn);
    unsigned short* orow = xbf + ((size_t)v * B_N + b) * D_N;
    reinterpret_cast<ushort4*>(orow)[t] = o;
}

// ------- Kernel 2: per-view X·X^T, row-wise argmax (off-diag), MFMA --------
// 128x128 tile per block, 4 waves (2x2), 16x16x32 bf16 MFMA, BK=64.
__global__ __launch_bounds__(256) void kargmax(const unsigned short* __restrict__ xbf,
                                               unsigned long long* __restrict__ rowmax) {
    __shared__ unsigned short lA[128 * 64];
    __shared__ unsigned short lB[128 * 64];
    const int v = blockIdx.y;
    const int bx = blockIdx.x;
    const int i0 = (bx >> 5) * 128;
    const int j0 = (bx & 31) * 128;
    const unsigned short* Xv = xbf + (size_t)v * B_N * D_N;

    const int tid = threadIdx.x;
    const int wid = tid >> 6, lane = tid & 63;
    const int wr = wid >> 1, wc = wid & 1;

    f32x4 acc[4][4];
    #pragma unroll
    for (int m = 0; m < 4; m++)
        #pragma unroll
        for (int n = 0; n < 4; n++) acc[m][n] = (f32x4){0.f, 0.f, 0.f, 0.f};

    const int srow = lane >> 3;         // 0..7 within an 8-row chunk
    const int scol = (lane & 7) * 8;    // element col offset (16B per lane)

    for (int kt = 0; kt < D_N; kt += 64) {
        #pragma unroll
        for (int c = 0; c < 4; ++c) {
            int chunk = wid * 4 + c;    // 0..15, 8 rows each
            int row = chunk * 8 + srow;
            const unsigned short* ga = Xv + (size_t)(i0 + row) * D_N + kt + scol;
            const unsigned short* gb = Xv + (size_t)(j0 + row) * D_N + kt + scol;
            __builtin_amdgcn_global_load_lds(
                (const __attribute__((address_space(1))) unsigned int*)ga,
                (__attribute__((address_space(3))) unsigned int*)&lA[chunk * 512], 16, 0, 0);
            __builtin_amdgcn_global_load_lds(
                (const __attribute__((address_space(1))) unsigned int*)gb,
                (__attribute__((address_space(3))) unsigned int*)&lB[chunk * 512], 16, 0, 0);
        }
        __syncthreads();
        #pragma unroll
        for (int kk = 0; kk < 64; kk += 32) {
            short8 af[4], bfr[4];
            #pragma unroll
            for (int m = 0; m < 4; m++)
                af[m] = *reinterpret_cast<const short8*>(
                    &lA[(wr * 64 + m * 16 + (lane & 15)) * 64 + kk + (lane >> 4) * 8]);
            #pragma unroll
            for (int n = 0; n < 4; n++)
                bfr[n] = *reinterpret_cast<const short8*>(
                    &lB[(wc * 64 + n * 16 + (lane & 15)) * 64 + kk + (lane >> 4) * 8]);
            #pragma unroll
            for (int m = 0; m < 4; m++)
                #pragma unroll
                for (int n = 0; n < 4; n++)
                    acc[m][n] = __builtin_amdgcn_mfma_f32_16x16x32_bf16(af[m], bfr[n], acc[m][n], 0, 0, 0);
        }
        __syncthreads();
    }

    // Epilogue: per-row packed max reduce + atomic.
    // C/D layout: col = lane&15, row = (lane>>4)*4 + reg  [m89/m91-verified]
    #pragma unroll
    for (int m = 0; m < 4; m++) {
        int rbase = i0 + wr * 64 + m * 16;
        #pragma unroll
        for (int j = 0; j < 4; j++) {
            int grow = rbase + (lane >> 4) * 4 + j;
            unsigned long long best = 0ull;
            #pragma unroll
            for (int n = 0; n < 4; n++) {
                int gcol = j0 + wc * 64 + n * 16 + (lane & 15);
                float vdot = acc[m][n][j];
                unsigned long long p = (grow == gcol)
                    ? 0ull
                    : ((unsigned long long)f2mono(vdot) << 32) | (unsigned int)(~(unsigned int)gcol);
                best = p > best ? p : best;
            }
            #pragma unroll
            for (int s = 1; s < 16; s <<= 1) {
                unsigned long long o = shfl_xor_u64(best, s);
                best = o > best ? o : best;
            }
            if ((lane & 15) == 0)
                atomicMax(&rowmax[(size_t)v * B_N + grow], best);
        }
    }
}

// ------ Kernel 3: exact fp32 distance for selected pairs, per-row loss -----
__global__ __launch_bounds__(256) void kdist(const float* __restrict__ x,
                                             const unsigned long long* __restrict__ rowmax,
                                             float* __restrict__ loss) {
    int idx = blockIdx.x;              // v*B + b
    int v = idx >> 12;
    int b = idx & (B_N - 1);
    unsigned long long p = rowmax[idx];
    int j = (int)(~(unsigned int)(p & 0xffffffffull));
    const float* pa = x + ((size_t)b * V_N + v) * D_N;
    const float* pc = x + ((size_t)j * V_N + v) * D_N;
    int t = threadIdx.x;
    float4 a = reinterpret_cast<const float4*>(pa)[t];
    float4 c = reinterpret_cast<const float4*>(pc)[t];
    float saa = a.x * a.x + a.y * a.y + a.z * a.z + a.w * a.w;
    float scc = c.x * c.x + c.y * c.y + c.z * c.z + c.w * c.w;
    float sac = a.x * c.x + a.y * c.y + a.z * c.z + a.w * c.w;
    #pragma unroll
    for (int s = 32; s > 0; s >>= 1) {
        saa += __shfl_xor(saa, s, 64);
        scc += __shfl_xor(scc, s, 64);
        sac += __shfl_xor(sac, s, 64);
    }
    __shared__ float r0[4], r1[4], r2[4];
    if ((t & 63) == 0) { r0[t >> 6] = saa; r1[t >> 6] = scc; r2[t >> 6] = sac; }
    __syncthreads();
    if (t == 0) {
        saa = r0[0] + r0[1] + r0[2] + r0[3];
        scc = r1[0] + r1[1] + r1[2] + r1[3];
        sac = r2[0] + r2[1] + r2[2] + r2[3];
        float na = sqrtf(saa + EPS), nc = sqrtf(scc + EPS);
        float d2 = saa / (na * na) + scc / (nc * nc) - 2.0f * sac / (na * nc);
        d2 = fmaxf(d2, 0.0f);
        float dist = sqrtf(d2);
        loss[idx] = -logf(dist + EPS);
    }
}

// --------------- Kernel 4: deterministic reduction to scalar ---------------
__global__ __launch_bounds__(256) void kreduce(const float* __restrict__ loss,
                                               float* __restrict__ out) {
    __shared__ float s[256];
    float acc = 0.f;
    for (int i = threadIdx.x; i < V_N * B_N; i += 256) acc += loss[i];
    s[threadIdx.x] = acc;
    __syncthreads();
    #pragma unroll
    for (int step = 128; step > 0; step >>= 1) {
        if (threadIdx.x < step) s[threadIdx.x] += s[threadIdx.x + step];
        __syncthreads();
    }
    if (threadIdx.x == 0) out[0] = s[0] * (1.0f / (float)B_N);
}

extern "C" void kernel_launch(void* const* d_in, const int* in_sizes, int n_in,
                              void* d_out, int out_size, void* d_ws, size_t ws_size,
                              hipStream_t stream) {
    const float* x = (const float*)d_in[0];
    float* out = (float*)d_out;
    char* ws = (char*)d_ws;

    unsigned short* xbf = (unsigned short*)ws;                          // 16 MB
    unsigned long long* rowmax = (unsigned long long*)(ws + 16777216);  // 64 KB
    float* loss = (float*)(ws + 16777216 + 65536);                      // 32 KB

    hipMemsetAsync(rowmax, 0, (size_t)V_N * B_N * sizeof(unsigned long long), stream);
    knorm<<<B_N * V_N, 256, 0, stream>>>(x, xbf);
    kargmax<<<dim3((B_N / 128) * (B_N / 128), V_N), 256, 0, stream>>>(xbf, rowmax);
    kdist<<<V_N * B_N, 256, 0, stream>>>(x, rowmax, loss);
    kreduce<<<1, 256, 0, stream>>>(loss, out);
}

// Round 2
// 113.667 us; speedup vs baseline: 1.3576x; 1.3576x over previous
//
#include <hip/hip_runtime.h>
#include <hip/hip_bf16.h>
#include <stdint.h>

#define B_N 4096
#define V_N 2
#define D_N 1024
#define EPS 1e-8f
#define NT 32            // 4096/128 tiles per dim
#define NTRI (NT*(NT+1)/2)

typedef __attribute__((ext_vector_type(8))) short short8;
typedef __attribute__((ext_vector_type(4))) float f32x4;

__device__ __forceinline__ unsigned int f2mono(float f) {
    unsigned int u = __float_as_uint(f);
    return (u & 0x80000000u) ? ~u : (u | 0x80000000u);
}

__device__ __forceinline__ unsigned short f2bf(float f) {
    __hip_bfloat16 h = __float2bfloat16(f);
    return __builtin_bit_cast(unsigned short, h);
}

__device__ __forceinline__ unsigned long long shfl_xor_u64(unsigned long long v, int m) {
    unsigned int lo = (unsigned int)v, hi = (unsigned int)(v >> 32);
    lo = __shfl_xor(lo, m, 64);
    hi = __shfl_xor(hi, m, 64);
    return ((unsigned long long)hi << 32) | lo;
}

// ---------------- Kernel 1: L2-normalize, emit bf16 (V,B,D) ----------------
__global__ __launch_bounds__(256) void knorm(const float* __restrict__ x,
                                             unsigned short* __restrict__ xbf) {
    int r = blockIdx.x;            // r = b*V + v  (input rows are contiguous)
    int b = r >> 1, v = r & 1;
    const float* row = x + (size_t)r * D_N;
    int t = threadIdx.x;
    float4 val = reinterpret_cast<const float4*>(row)[t];
    float ss = val.x * val.x + val.y * val.y + val.z * val.z + val.w * val.w;
    #pragma unroll
    for (int s = 32; s > 0; s >>= 1) ss += __shfl_xor(ss, s, 64);
    __shared__ float wsum[4];
    if ((t & 63) == 0) wsum[t >> 6] = ss;
    __syncthreads();
    float tot = wsum[0] + wsum[1] + wsum[2] + wsum[3];
    float rn = 1.0f / sqrtf(tot + EPS);
    ushort4 o;
    o.x = f2bf(val.x * rn);
    o.y = f2bf(val.y * rn);
    o.z = f2bf(val.z * rn);
    o.w = f2bf(val.w * rn);
    unsigned short* orow = xbf + ((size_t)v * B_N + b) * D_N;
    reinterpret_cast<ushort4*>(orow)[t] = o;
}

// ------- Kernel 2: per-view X·X^T, row-wise argmax, symmetric tiles --------
// Lower-triangle 128x128 tiles, 4 waves (2x2), 16x16x32 bf16 MFMA, BK=64.
// LDS XOR-swizzled (write side via pre-swizzled global source, rule #21).
__global__ __launch_bounds__(256) void kargmax(const unsigned short* __restrict__ xbf,
                                               unsigned long long* __restrict__ rowmax) {
    __shared__ unsigned short lA[128 * 64];
    __shared__ unsigned short lB[128 * 64];
    const int v = blockIdx.y;
    const int bx = blockIdx.x;           // 0..NTRI-1, lower triangle incl diag
    int ti = (int)((sqrtf(8.f * (float)bx + 1.f) - 1.f) * 0.5f);
    while ((ti + 1) * (ti + 2) / 2 <= bx) ti++;
    while (ti * (ti + 1) / 2 > bx) ti--;
    const int tj = bx - ti * (ti + 1) / 2;
    const int i0 = ti * 128;
    const int j0 = tj * 128;
    const bool diag = (ti == tj);
    const unsigned short* Xv = xbf + (size_t)v * B_N * D_N;

    const int tid = threadIdx.x;
    const int wid = tid >> 6, lane = tid & 63;
    const int wr = wid >> 1, wc = wid & 1;

    f32x4 acc[4][4];
    #pragma unroll
    for (int m = 0; m < 4; m++)
        #pragma unroll
        for (int n = 0; n < 4; n++) acc[m][n] = (f32x4){0.f, 0.f, 0.f, 0.f};

    const int srow = lane >> 3;                       // 0..7 within an 8-row chunk
    const int scol = ((lane & 7) ^ srow) * 8;         // XOR-swizzled 16B slot (T2)

    for (int kt = 0; kt < D_N; kt += 64) {
        #pragma unroll
        for (int c = 0; c < 4; ++c) {
            int chunk = wid * 4 + c;    // 0..15, 8 rows each
            int row = chunk * 8 + srow;
            const unsigned short* ga = Xv + (size_t)(i0 + row) * D_N + kt + scol;
            const unsigned short* gb = Xv + (size_t)(j0 + row) * D_N + kt + scol;
            __builtin_amdgcn_global_load_lds(
                (const __attribute__((address_space(1))) unsigned int*)ga,
                (__attribute__((address_space(3))) unsigned int*)&lA[chunk * 512], 16, 0, 0);
            __builtin_amdgcn_global_load_lds(
                (const __attribute__((address_space(1))) unsigned int*)gb,
                (__attribute__((address_space(3))) unsigned int*)&lB[chunk * 512], 16, 0, 0);
        }
        __syncthreads();
        #pragma unroll
        for (int kk = 0; kk < 64; kk += 32) {
            short8 af[4], bfr[4];
            #pragma unroll
            for (int m = 0; m < 4; m++) {
                int ar = wr * 64 + m * 16 + (lane & 15);
                int slot = ((kk >> 3) + (lane >> 4)) ^ (ar & 7);
                af[m] = *reinterpret_cast<const short8*>(&lA[ar * 64 + slot * 8]);
            }
            #pragma unroll
            for (int n = 0; n < 4; n++) {
                int br = wc * 64 + n * 16 + (lane & 15);
                int slot = ((kk >> 3) + (lane >> 4)) ^ (br & 7);
                bfr[n] = *reinterpret_cast<const short8*>(&lB[br * 64 + slot * 8]);
            }
            #pragma unroll
            for (int m = 0; m < 4; m++)
                #pragma unroll
                for (int n = 0; n < 4; n++)
                    acc[m][n] = __builtin_amdgcn_mfma_f32_16x16x32_bf16(af[m], bfr[n], acc[m][n], 0, 0, 0);
        }
        __syncthreads();
    }

    // ---- Epilogue A: row side (rows i0.., cols j0..) ----
    // C/D layout: col = lane&15, row = (lane>>4)*4 + reg  [m89/m91-verified]
    #pragma unroll
    for (int m = 0; m < 4; m++) {
        int rbase = i0 + wr * 64 + m * 16;
        #pragma unroll
        for (int j = 0; j < 4; j++) {
            int grow = rbase + (lane >> 4) * 4 + j;
            unsigned long long best = 0ull;
            #pragma unroll
            for (int n = 0; n < 4; n++) {
                int gcol = j0 + wc * 64 + n * 16 + (lane & 15);
                float vdot = acc[m][n][j];
                unsigned long long p = (grow == gcol)
                    ? 0ull
                    : ((unsigned long long)f2mono(vdot) << 32) | (unsigned int)(~(unsigned int)gcol);
                best = p > best ? p : best;
            }
            #pragma unroll
            for (int s = 1; s < 16; s <<= 1) {
                unsigned long long o = shfl_xor_u64(best, s);
                best = o > best ? o : best;
            }
            if ((lane & 15) == 0)
                atomicMax(&rowmax[(size_t)v * B_N + grow], best);
        }
    }

    // ---- Epilogue B: transposed side (rows j0.., cols i0..), off-diag only ----
    if (!diag) {
        #pragma unroll
        for (int n = 0; n < 4; n++) {
            int growT = j0 + wc * 64 + n * 16 + (lane & 15);   // C column = transposed row
            unsigned long long best = 0ull;
            #pragma unroll
            for (int m = 0; m < 4; m++) {
                int ibase = i0 + wr * 64 + m * 16 + (lane >> 4) * 4;
                #pragma unroll
                for (int j = 0; j < 4; j++) {
                    int gi = ibase + j;                        // C row = transposed col
                    float vdot = acc[m][n][j];
                    unsigned long long p =
                        ((unsigned long long)f2mono(vdot) << 32) | (unsigned int)(~(unsigned int)gi);
                    best = p > best ? p : best;
                }
            }
            #pragma unroll
            for (int s = 16; s < 64; s <<= 1) {
                unsigned long long o = shfl_xor_u64(best, s);
                best = o > best ? o : best;
            }
            if (lane < 16)
                atomicMax(&rowmax[(size_t)v * B_N + growT], best);
        }
    }
}

// ------ Kernel 3: exact fp32 distance for selected pairs, per-row loss -----
__global__ __launch_bounds__(256) void kdist(const float* __restrict__ x,
                                             const unsigned long long* __restrict__ rowmax,
                                             float* __restrict__ loss) {
    int idx = blockIdx.x;              // v*B + b
    int v = idx >> 12;
    int b = idx & (B_N - 1);
    unsigned long long p = rowmax[idx];
    int j = (int)(~(unsigned int)(p & 0xffffffffull));
    const float* pa = x + ((size_t)b * V_N + v) * D_N;
    const float* pc = x + ((size_t)j * V_N + v) * D_N;
    int t = threadIdx.x;
    float4 a = reinterpret_cast<const float4*>(pa)[t];
    float4 c = reinterpret_cast<const float4*>(pc)[t];
    float saa = a.x * a.x + a.y * a.y + a.z * a.z + a.w * a.w;
    float scc = c.x * c.x + c.y * c.y + c.z * c.z + c.w * c.w;
    float sac = a.x * c.x + a.y * c.y + a.z * c.z + a.w * c.w;
    #pragma unroll
    for (int s = 32; s > 0; s >>= 1) {
        saa += __shfl_xor(saa, s, 64);
        scc += __shfl_xor(scc, s, 64);
        sac += __shfl_xor(sac, s, 64);
    }
    __shared__ float r0[4], r1[4], r2[4];
    if ((t & 63) == 0) { r0[t >> 6] = saa; r1[t >> 6] = scc; r2[t >> 6] = sac; }
    __syncthreads();
    if (t == 0) {
        saa = r0[0] + r0[1] + r0[2] + r0[3];
        scc = r1[0] + r1[1] + r1[2] + r1[3];
        sac = r2[0] + r2[1] + r2[2] + r2[3];
        float na = sqrtf(saa + EPS), nc = sqrtf(scc + EPS);
        float d2 = saa / (na * na) + scc / (nc * nc) - 2.0f * sac / (na * nc);
        d2 = fmaxf(d2, 0.0f);
        float dist = sqrtf(d2);
        loss[idx] = -logf(dist + EPS);
    }
}

// --------------- Kernel 4: deterministic reduction to scalar ---------------
__global__ __launch_bounds__(256) void kreduce(const float* __restrict__ loss,
                                               float* __restrict__ out) {
    __shared__ float s[256];
    float acc = 0.f;
    for (int i = threadIdx.x; i < V_N * B_N; i += 256) acc += loss[i];
    s[threadIdx.x] = acc;
    __syncthreads();
    #pragma unroll
    for (int step = 128; step > 0; step >>= 1) {
        if (threadIdx.x < step) s[threadIdx.x] += s[threadIdx.x + step];
        __syncthreads();
    }
    if (threadIdx.x == 0) out[0] = s[0] * (1.0f / (float)B_N);
}

extern "C" void kernel_launch(void* const* d_in, const int* in_sizes, int n_in,
                              void* d_out, int out_size, void* d_ws, size_t ws_size,
                              hipStream_t stream) {
    const float* x = (const float*)d_in[0];
    float* out = (float*)d_out;
    char* ws = (char*)d_ws;

    unsigned short* xbf = (unsigned short*)ws;                          // 16 MB
    unsigned long long* rowmax = (unsigned long long*)(ws + 16777216);  // 64 KB
    float* loss = (float*)(ws + 16777216 + 65536);                      // 32 KB

    hipMemsetAsync(rowmax, 0, (size_t)V_N * B_N * sizeof(unsigned long long), stream);
    knorm<<<B_N * V_N, 256, 0, stream>>>(x, xbf);
    kargmax<<<dim3(NTRI, V_N), 256, 0, stream>>>(xbf, rowmax);
    kdist<<<V_N * B_N, 256, 0, stream>>>(x, rowmax, loss);
    kreduce<<<1, 256, 0, stream>>>(loss, out);
}

// Round 3
// 107.222 us; speedup vs baseline: 1.4392x; 1.0601x over previous
//
#include <hip/hip_runtime.h>
#include <hip/hip_bf16.h>
#include <stdint.h>

#define B_N 4096
#define V_N 2
#define D_N 1024
#define EPS 1e-8f
#define NT 32            // 4096/128 tiles per dim
#define NTRI (NT*(NT+1)/2)   // 528, divisible by 8 -> clean XCD chunking

typedef __attribute__((ext_vector_type(8))) short short8;
typedef __attribute__((ext_vector_type(4))) float f32x4;

__device__ __forceinline__ unsigned int f2mono(float f) {
    unsigned int u = __float_as_uint(f);
    return (u & 0x80000000u) ? ~u : (u | 0x80000000u);
}

__device__ __forceinline__ unsigned short f2bf(float f) {
    __hip_bfloat16 h = __float2bfloat16(f);
    return __builtin_bit_cast(unsigned short, h);
}

__device__ __forceinline__ unsigned long long shfl_xor_u64(unsigned long long v, int m) {
    unsigned int lo = (unsigned int)v, hi = (unsigned int)(v >> 32);
    lo = __shfl_xor(lo, m, 64);
    hi = __shfl_xor(hi, m, 64);
    return ((unsigned long long)hi << 32) | lo;
}

// ---------------- Kernel 1: L2-normalize, emit bf16 (V,B,D) ----------------
__global__ __launch_bounds__(256) void knorm(const float* __restrict__ x,
                                             unsigned short* __restrict__ xbf) {
    int r = blockIdx.x;            // r = b*V + v  (input rows are contiguous)
    int b = r >> 1, v = r & 1;
    const float* row = x + (size_t)r * D_N;
    int t = threadIdx.x;
    float4 val = reinterpret_cast<const float4*>(row)[t];
    float ss = val.x * val.x + val.y * val.y + val.z * val.z + val.w * val.w;
    #pragma unroll
    for (int s = 32; s > 0; s >>= 1) ss += __shfl_xor(ss, s, 64);
    __shared__ float wsum[4];
    if ((t & 63) == 0) wsum[t >> 6] = ss;
    __syncthreads();
    float tot = wsum[0] + wsum[1] + wsum[2] + wsum[3];
    float rn = 1.0f / sqrtf(tot + EPS);
    ushort4 o;
    o.x = f2bf(val.x * rn);
    o.y = f2bf(val.y * rn);
    o.z = f2bf(val.z * rn);
    o.w = f2bf(val.w * rn);
    unsigned short* orow = xbf + ((size_t)v * B_N + b) * D_N;
    reinterpret_cast<ushort4*>(orow)[t] = o;
}

// ------- Kernel 2: per-view X·X^T, row-wise argmax, symmetric tiles --------
// Lower-triangle 128x128 tiles, 4 waves (2x2), 16x16x32 bf16 MFMA, BK=64.
// T3-minimum 2-phase double-buffered pipeline; T2 XOR-swizzled LDS
// (write side via pre-swizzled global source, rule #21); T1 XCD chunking.
#define STAGE(bufidx, ktelem) do {                                                        \
    _Pragma("unroll")                                                                     \
    for (int c = 0; c < 4; ++c) {                                                         \
        int chunk = wid * 4 + c;                                                          \
        int row = chunk * 8 + srow;                                                       \
        const unsigned short* ga = Xv + (size_t)(i0 + row) * D_N + (ktelem) + scol;       \
        const unsigned short* gb = Xv + (size_t)(j0 + row) * D_N + (ktelem) + scol;       \
        __builtin_amdgcn_global_load_lds(                                                 \
            (const __attribute__((address_space(1))) unsigned int*)ga,                    \
            (__attribute__((address_space(3))) unsigned int*)&lA[bufidx][chunk * 512],    \
            16, 0, 0);                                                                    \
        __builtin_amdgcn_global_load_lds(                                                 \
            (const __attribute__((address_space(1))) unsigned int*)gb,                    \
            (__attribute__((address_space(3))) unsigned int*)&lB[bufidx][chunk * 512],    \
            16, 0, 0);                                                                    \
    }                                                                                     \
} while (0)

#define COMPUTE(bufidx) do {                                                              \
    _Pragma("unroll")                                                                     \
    for (int kk = 0; kk < 64; kk += 32) {                                                 \
        short8 af[4], bfr[4];                                                             \
        _Pragma("unroll")                                                                 \
        for (int m = 0; m < 4; m++) {                                                     \
            int ar = wr * 64 + m * 16 + (lane & 15);                                      \
            int slot = ((kk >> 3) + (lane >> 4)) ^ (ar & 7);                              \
            af[m] = *reinterpret_cast<const short8*>(&lA[bufidx][ar * 64 + slot * 8]);    \
        }                                                                                 \
        _Pragma("unroll")                                                                 \
        for (int n = 0; n < 4; n++) {                                                     \
            int br = wc * 64 + n * 16 + (lane & 15);                                      \
            int slot = ((kk >> 3) + (lane >> 4)) ^ (br & 7);                              \
            bfr[n] = *reinterpret_cast<const short8*>(&lB[bufidx][br * 64 + slot * 8]);   \
        }                                                                                 \
        _Pragma("unroll")                                                                 \
        for (int m = 0; m < 4; m++)                                                       \
            _Pragma("unroll")                                                             \
            for (int n = 0; n < 4; n++)                                                   \
                acc[m][n] = __builtin_amdgcn_mfma_f32_16x16x32_bf16(af[m], bfr[n],        \
                                                                    acc[m][n], 0, 0, 0); \
    }                                                                                     \
} while (0)

__global__ __launch_bounds__(256, 2) void kargmax(const unsigned short* __restrict__ xbf,
                                                  unsigned long long* __restrict__ rowmax) {
    __shared__ unsigned short lA[2][128 * 64];
    __shared__ unsigned short lB[2][128 * 64];
    const int v = blockIdx.y;
    // T1: chunked XCD swizzle (bijective: 528 = 8*66)
    const int bx = (blockIdx.x & 7) * (NTRI / 8) + (blockIdx.x >> 3);
    int ti = (int)((sqrtf(8.f * (float)bx + 1.f) - 1.f) * 0.5f);
    while ((ti + 1) * (ti + 2) / 2 <= bx) ti++;
    while (ti * (ti + 1) / 2 > bx) ti--;
    const int tj = bx - ti * (ti + 1) / 2;
    const int i0 = ti * 128;
    const int j0 = tj * 128;
    const bool diag = (ti == tj);
    const unsigned short* Xv = xbf + (size_t)v * B_N * D_N;

    const int tid = threadIdx.x;
    const int wid = tid >> 6, lane = tid & 63;
    const int wr = wid >> 1, wc = wid & 1;

    f32x4 acc[4][4];
    #pragma unroll
    for (int m = 0; m < 4; m++)
        #pragma unroll
        for (int n = 0; n < 4; n++) acc[m][n] = (f32x4){0.f, 0.f, 0.f, 0.f};

    const int srow = lane >> 3;                       // 0..7 within an 8-row chunk
    const int scol = ((lane & 7) ^ srow) * 8;         // XOR-swizzled 16B slot (T2)

    // ---- 2-phase pipeline (T3 minimum): issue next stage BEFORE compute ----
    STAGE(0, 0);
    __syncthreads();                    // drains vmcnt(0): buf0 ready
    int cur = 0;
    for (int kt = 64; kt < D_N; kt += 64) {
        STAGE(cur ^ 1, kt);             // next tile's loads fly during compute
        COMPUTE(cur);
        __syncthreads();                // vmcnt(0)+lgkmcnt(0) drain + barrier
        cur ^= 1;
    }
    COMPUTE(cur);

    // ---- Epilogue A: row side (rows i0.., cols j0..) ----
    // C/D layout: col = lane&15, row = (lane>>4)*4 + reg  [m89/m91-verified]
    #pragma unroll
    for (int m = 0; m < 4; m++) {
        int rbase = i0 + wr * 64 + m * 16;
        #pragma unroll
        for (int j = 0; j < 4; j++) {
            int grow = rbase + (lane >> 4) * 4 + j;
            unsigned long long best = 0ull;
            #pragma unroll
            for (int n = 0; n < 4; n++) {
                int gcol = j0 + wc * 64 + n * 16 + (lane & 15);
                float vdot = acc[m][n][j];
                unsigned long long p = (grow == gcol)
                    ? 0ull
                    : ((unsigned long long)f2mono(vdot) << 32) | (unsigned int)(~(unsigned int)gcol);
                best = p > best ? p : best;
            }
            #pragma unroll
            for (int s = 1; s < 16; s <<= 1) {
                unsigned long long o = shfl_xor_u64(best, s);
                best = o > best ? o : best;
            }
            if ((lane & 15) == 0)
                atomicMax(&rowmax[(size_t)v * B_N + grow], best);
        }
    }

    // ---- Epilogue B: transposed side (rows j0.., cols i0..), off-diag only ----
    if (!diag) {
        #pragma unroll
        for (int n = 0; n < 4; n++) {
            int growT = j0 + wc * 64 + n * 16 + (lane & 15);   // C column = transposed row
            unsigned long long best = 0ull;
            #pragma unroll
            for (int m = 0; m < 4; m++) {
                int ibase = i0 + wr * 64 + m * 16 + (lane >> 4) * 4;
                #pragma unroll
                for (int j = 0; j < 4; j++) {
                    int gi = ibase + j;                        // C row = transposed col
                    float vdot = acc[m][n][j];
                    unsigned long long p =
                        ((unsigned long long)f2mono(vdot) << 32) | (unsigned int)(~(unsigned int)gi);
                    best = p > best ? p : best;
                }
            }
            #pragma unroll
            for (int s = 16; s < 64; s <<= 1) {
                unsigned long long o = shfl_xor_u64(best, s);
                best = o > best ? o : best;
            }
            if (lane < 16)
                atomicMax(&rowmax[(size_t)v * B_N + growT], best);
        }
    }
}

// ------ Kernel 3: exact fp32 distance for selected pairs, per-row loss -----
__global__ __launch_bounds__(256) void kdist(const float* __restrict__ x,
                                             const unsigned long long* __restrict__ rowmax,
                                             float* __restrict__ loss) {
    int idx = blockIdx.x;              // v*B + b
    int v = idx >> 12;
    int b = idx & (B_N - 1);
    unsigned long long p = rowmax[idx];
    int j = (int)(~(unsigned int)(p & 0xffffffffull));
    const float* pa = x + ((size_t)b * V_N + v) * D_N;
    const float* pc = x + ((size_t)j * V_N + v) * D_N;
    int t = threadIdx.x;
    float4 a = reinterpret_cast<const float4*>(pa)[t];
    float4 c = reinterpret_cast<const float4*>(pc)[t];
    float saa = a.x * a.x + a.y * a.y + a.z * a.z + a.w * a.w;
    float scc = c.x * c.x + c.y * c.y + c.z * c.z + c.w * c.w;
    float sac = a.x * c.x + a.y * c.y + a.z * c.z + a.w * c.w;
    #pragma unroll
    for (int s = 32; s > 0; s >>= 1) {
        saa += __shfl_xor(saa, s, 64);
        scc += __shfl_xor(scc, s, 64);
        sac += __shfl_xor(sac, s, 64);
    }
    __shared__ float r0[4], r1[4], r2[4];
    if ((t & 63) == 0) { r0[t >> 6] = saa; r1[t >> 6] = scc; r2[t >> 6] = sac; }
    __syncthreads();
    if (t == 0) {
        saa = r0[0] + r0[1] + r0[2] + r0[3];
        scc = r1[0] + r1[1] + r1[2] + r1[3];
        sac = r2[0] + r2[1] + r2[2] + r2[3];
        float na = sqrtf(saa + EPS), nc = sqrtf(scc + EPS);
        float d2 = saa / (na * na) + scc / (nc * nc) - 2.0f * sac / (na * nc);
        d2 = fmaxf(d2, 0.0f);
        float dist = sqrtf(d2);
        loss[idx] = -logf(dist + EPS);
    }
}

// --------------- Kernel 4: deterministic reduction to scalar ---------------
__global__ __launch_bounds__(256) void kreduce(const float* __restrict__ loss,
                                               float* __restrict__ out) {
    __shared__ float s[256];
    float acc = 0.f;
    for (int i = threadIdx.x; i < V_N * B_N; i += 256) acc += loss[i];
    s[threadIdx.x] = acc;
    __syncthreads();
    #pragma unroll
    for (int step = 128; step > 0; step >>= 1) {
        if (threadIdx.x < step) s[threadIdx.x] += s[threadIdx.x + step];
        __syncthreads();
    }
    if (threadIdx.x == 0) out[0] = s[0] * (1.0f / (float)B_N);
}

extern "C" void kernel_launch(void* const* d_in, const int* in_sizes, int n_in,
                              void* d_out, int out_size, void* d_ws, size_t ws_size,
                              hipStream_t stream) {
    const float* x = (const float*)d_in[0];
    float* out = (float*)d_out;
    char* ws = (char*)d_ws;

    unsigned short* xbf = (unsigned short*)ws;                          // 16 MB
    unsigned long long* rowmax = (unsigned long long*)(ws + 16777216);  // 64 KB
    float* loss = (float*)(ws + 16777216 + 65536);                      // 32 KB

    hipMemsetAsync(rowmax, 0, (size_t)V_N * B_N * sizeof(unsigned long long), stream);
    knorm<<<B_N * V_N, 256, 0, stream>>>(x, xbf);
    kargmax<<<dim3(NTRI, V_N), 256, 0, stream>>>(xbf, rowmax);
    kdist<<<V_N * B_N, 256, 0, stream>>>(x, rowmax, loss);
    kreduce<<<1, 256, 0, stream>>>(loss, out);
}